// Round 4
// baseline (157.156 us; speedup 1.0000x reference)
//
#include <hip/hip_runtime.h>
#include <hip/hip_bf16.h>

typedef __attribute__((ext_vector_type(8))) short bf16x8;
typedef __attribute__((ext_vector_type(4))) short bf16x4;
typedef __attribute__((ext_vector_type(4))) float f32x4;

__device__ __forceinline__ unsigned short f2bf(float f) {
    unsigned x = __float_as_uint(f);
    unsigned r = (x + 0x7FFF + ((x >> 16) & 1)) >> 16;   // RNE
    return (unsigned short)r;
}
// explicit float4 loads (hipcc does not reliably merge 8 scalar f32 loads)
__device__ __forceinline__ bf16x8 cvt8(const float* __restrict__ p) {
    float4 v0 = *(const float4*)p;
    float4 v1 = *(const float4*)(p + 4);
    bf16x8 r;
    r[0] = (short)f2bf(v0.x); r[1] = (short)f2bf(v0.y);
    r[2] = (short)f2bf(v0.z); r[3] = (short)f2bf(v0.w);
    r[4] = (short)f2bf(v1.x); r[5] = (short)f2bf(v1.y);
    r[6] = (short)f2bf(v1.z); r[7] = (short)f2bf(v1.w);
    return r;
}
__device__ __forceinline__ unsigned pack_relu_bf16(unsigned yv, unsigned zv) {
    float lo = fmaxf(__uint_as_float(yv << 16) + __uint_as_float(zv << 16), 0.0f);
    float hi = fmaxf(__uint_as_float(yv & 0xFFFF0000u) + __uint_as_float(zv & 0xFFFF0000u), 0.0f);
    __hip_bfloat162 p = __float22bfloat162_rn(float2{lo, hi});
    return *(unsigned*)&p;
}

// ---------------- kernel B (all-in-one prep): grid sections ----------------------
// [0, yblk)            : u2e->bf16 writeback + Y = u2e@W1_top  (stage TOP half of W1)
// [yblk, yblk+zblk)    : z[n] = u2e[nodes[n]]@W1_bot + b1      (stage BOTTOM half of W1)
// yblk+zblk            : w2t transpose
// (yblk+zblk, ...)     : seg_off binary search
// Grid-stride over 64-row tiles (round-1 blocking, best measured); MFMA computed
// TRANSPOSED (W1T as A, data as B): same k-order products => bit-identical, but
// each lane holds 4 consecutive channels of ONE row -> 4 x 8B vector stores.
template <bool BF>
__launch_bounds__(256)
__global__ void conv_all_k(const float* __restrict__ u2e,
                           const int* __restrict__ nodes,
                           const int* __restrict__ segs,
                           const float* __restrict__ w1,
                           const float* __restrict__ w2,
                           const float* __restrict__ b1f,
                           unsigned short* __restrict__ u2ebf,
                           unsigned short* __restrict__ Y,
                           unsigned short* __restrict__ z,
                           unsigned short* __restrict__ w2t,
                           int* __restrict__ seg_off,
                           int V, int N, int E, int yblk, int zblk,
                           int ytiles, int ztiles) {
    __shared__ __align__(16) unsigned short w1l[64 * 72];
    const int bid = blockIdx.x;
    const int t = threadIdx.x;
    const int wid = t >> 6;
    const int lane = t & 63;
    const int q = lane >> 4;
    const int m15 = lane & 15;

    if (bid < yblk + zblk) {
        const bool isY = bid < yblk;
        const int kbase = isY ? 0 : 64;
        for (int u = t; u < 64 * 16; u += 256) {
            int k = u >> 4;
            int n4 = (u & 15) * 4;
            float4 v = *(const float4*)(w1 + (long)(kbase + k) * 64 + n4);
            w1l[(n4 + 0) * 72 + k] = f2bf(v.x);
            w1l[(n4 + 1) * 72 + k] = f2bf(v.y);
            w1l[(n4 + 2) * 72 + k] = f2bf(v.z);
            w1l[(n4 + 3) * 72 + k] = f2bf(v.w);
        }
        __syncthreads();

        // W1T fragments (A operand): lane m15 = output channel b*16+m15, k-chunk q*8
        bf16x8 wb0[4], wb1[4];
#pragma unroll
        for (int b = 0; b < 4; ++b) {
            const unsigned short* wr = w1l + (b * 16 + m15) * 72;
            wb0[b] = *(const bf16x8*)(wr + q * 8);
            wb1[b] = *(const bf16x8*)(wr + 32 + q * 8);
        }

        if (isY) {
            for (int tile = bid; tile < ytiles; tile += yblk) {
                const int wbase = tile * 64 + wid * 16;
                if (wbase >= V) continue;
                const bool ok = wbase + m15 < V;
                int row = min(wbase + m15, V - 1);
                const float* p = u2e + (long)row * 64;
                bf16x8 a0 = cvt8(p + q * 8);
                bf16x8 a1 = cvt8(p + 32 + q * 8);
                if (BF && ok) {
                    *(bf16x8*)(u2ebf + (long)row * 64 + q * 8) = a0;
                    *(bf16x8*)(u2ebf + (long)row * 64 + 32 + q * 8) = a1;
                }
                f32x4 acc[4];
#pragma unroll
                for (int b = 0; b < 4; ++b) {
                    acc[b] = (f32x4){0.f, 0.f, 0.f, 0.f};
                    acc[b] = __builtin_amdgcn_mfma_f32_16x16x32_bf16(wb0[b], a0, acc[b], 0, 0, 0);
                    acc[b] = __builtin_amdgcn_mfma_f32_16x16x32_bf16(wb1[b], a1, acc[b], 0, 0, 0);
                }
                if (ok) {
                    unsigned short* yr = Y + (long)(wbase + m15) * 64;
#pragma unroll
                    for (int b = 0; b < 4; ++b) {
                        bf16x4 o = {(short)f2bf(acc[b][0]), (short)f2bf(acc[b][1]),
                                    (short)f2bf(acc[b][2]), (short)f2bf(acc[b][3])};
                        *(bf16x4*)(yr + b * 16 + q * 4) = o;
                    }
                }
            }
        } else {
            for (int tile = bid - yblk; tile < ztiles; tile += zblk) {
                const int wbase = tile * 64 + wid * 16;
                if (wbase >= N) continue;
                const bool ok = wbase + m15 < N;
                int nd = nodes[min(wbase + m15, N - 1)];
                const float* p = u2e + (long)nd * 64;
                bf16x8 a0 = cvt8(p + q * 8);
                bf16x8 a1 = cvt8(p + 32 + q * 8);
                f32x4 acc[4];
#pragma unroll
                for (int b = 0; b < 4; ++b) {
                    acc[b] = *(const f32x4*)(b1f + b * 16 + q * 4);   // bias per channel
                    acc[b] = __builtin_amdgcn_mfma_f32_16x16x32_bf16(wb0[b], a0, acc[b], 0, 0, 0);
                    acc[b] = __builtin_amdgcn_mfma_f32_16x16x32_bf16(wb1[b], a1, acc[b], 0, 0, 0);
                }
                if (ok) {
                    unsigned short* zr = z + (long)(wbase + m15) * 64;
#pragma unroll
                    for (int b = 0; b < 4; ++b) {
                        bf16x4 o = {(short)f2bf(acc[b][0]), (short)f2bf(acc[b][1]),
                                    (short)f2bf(acc[b][2]), (short)f2bf(acc[b][3])};
                        *(bf16x4*)(zr + b * 16 + q * 4) = o;
                    }
                }
            }
        }
    } else if (bid == yblk + zblk) {
        for (int i = t; i < 64 * 64; i += 256) {
            int k = i >> 6, n = i & 63;
            w2t[n * 64 + k] = f2bf(w2[i]);
        }
    } else {
        int idx = (bid - yblk - zblk - 1) * 256 + t;
        if (idx > N) return;
        int l = 0, r = E;
        while (l < r) { int mid = (l + r) >> 1; if (segs[mid] < idx) l = mid + 1; else r = mid; }
        seg_off[idx] = l;
    }
}

// ---------------- kernel 1: per-edge MLP, 32 edges/wave (2x16 groups) -----------
__launch_bounds__(256)
__global__ void logits2_k(const int* __restrict__ neigh,
                          const int* __restrict__ segs,
                          const unsigned short* __restrict__ Y,
                          const unsigned short* __restrict__ z,
                          const unsigned short* __restrict__ w2t,
                          const float* __restrict__ b2f,
                          const float* __restrict__ w3f, const float* __restrict__ b3f,
                          float* __restrict__ ex, int E) {
    const int wid = threadIdx.x >> 6;
    const int lane = threadIdx.x & 63;
    const int q = lane >> 4;
    const int m15 = lane & 15;
    const long base = ((long)blockIdx.x * 4 + wid) * 32;
    if (base >= E) return;

    int vi[2], sg[2];
#pragma unroll
    for (int g = 0; g < 2; ++g) {
        long e = base + g * 16 + m15;
        int ec = (int)(e < E ? e : (long)E - 1);
        vi[g] = neigh[ec];
        sg[g] = segs[ec];
    }
    bf16x8 y0[2], y1[2], zz0[2], zz1[2];
#pragma unroll
    for (int g = 0; g < 2; ++g) {
        const unsigned short* yr = Y + (long)vi[g] * 64;
        y0[g] = *(const bf16x8*)(yr + q * 8);
        y1[g] = *(const bf16x8*)(yr + 32 + q * 8);
        const unsigned short* zr = z + (long)sg[g] * 64;
        zz0[g] = *(const bf16x8*)(zr + q * 8);
        zz1[g] = *(const bf16x8*)(zr + 32 + q * 8);
    }

    float b2v[4], w3v[4];
#pragma unroll
    for (int b = 0; b < 4; ++b) {
        b2v[b] = b2f[b * 16 + m15];
        w3v[b] = w3f[b * 16 + m15];
    }

    f32x4 acc[2][4];
#pragma unroll
    for (int g = 0; g < 2; ++g) {
        bf16x8 h0, h1;
#pragma unroll
        for (int j = 0; j < 4; ++j) {
            ((unsigned*)&h0)[j] = pack_relu_bf16(((unsigned*)&y0[g])[j], ((unsigned*)&zz0[g])[j]);
            ((unsigned*)&h1)[j] = pack_relu_bf16(((unsigned*)&y1[g])[j], ((unsigned*)&zz1[g])[j]);
        }
#pragma unroll
        for (int b = 0; b < 4; ++b) {
            acc[g][b] = (f32x4){b2v[b], b2v[b], b2v[b], b2v[b]};
            const bf16x8* wrow = (const bf16x8*)(w2t + (b * 16 + m15) * 64);
            acc[g][b] = __builtin_amdgcn_mfma_f32_16x16x32_bf16(h0, wrow[0 + q], acc[g][b], 0, 0, 0);
            acc[g][b] = __builtin_amdgcn_mfma_f32_16x16x32_bf16(h1, wrow[4 + q], acc[g][b], 0, 0, 0);
        }
    }

    const float b3v = b3f[0];
#pragma unroll
    for (int g = 0; g < 2; ++g)
#pragma unroll
        for (int r = 0; r < 4; ++r) {
            float v = 0.0f;
#pragma unroll
            for (int b = 0; b < 4; ++b) v += fmaxf(acc[g][b][r], 0.0f) * w3v[b];
            v += __shfl_xor(v, 1);
            v += __shfl_xor(v, 2);
            v += __shfl_xor(v, 4);
            v += __shfl_xor(v, 8);
            long ee = base + g * 16 + q * 4 + r;
            if (m15 == r && ee < E) ex[ee] = __expf(v + b3v);
        }
}

// ---------------- kernel 2: wave-per-node weighted segment sum ------------------
// BF path: 16 slots x 4 channel-lanes (16 ch each). ex/neigh for the first 64
// edges prefetched with TWO coalesced loads, redistributed by shfl (VALU only);
// all 8 row-chunk gathers issue back-to-back (zero-weight masking, no branches).
// Serial memory depth per node: ~1 round-trip (was ~4).
template <bool BF>
__launch_bounds__(256)
__global__ void aggw_k(const int* __restrict__ seg_off,
                       const int* __restrict__ neigh,
                       const unsigned short* __restrict__ u2ebf,
                       const float* __restrict__ u2e,
                       const float* __restrict__ ex,
                       float* __restrict__ out, int N) {
    const int wid = threadIdx.x >> 6;
    const int lane = threadIdx.x & 63;
    const int n = blockIdx.x * 4 + wid;
    if (n >= N) return;
    const int lo = seg_off[n];
    const int hi = seg_off[n + 1];

    if constexpr (BF) {
        const int slot = lane >> 2;      // 0..15, edge stride 16
        const int cl = lane & 3;         // 0..3, channels cl*16 .. cl*16+15
        const int deg = hi - lo;

        int idx = lo + lane;
        float exv = 0.f;
        int nv = 0;
        if (idx < hi) { exv = ex[idx]; nv = neigh[idx]; }

        float wk[4];
        int vk[4];
#pragma unroll
        for (int j = 0; j < 4; ++j) {
            int k = slot + 16 * j;
            int kc = k < deg ? k : 0;
            float w = __shfl(exv, kc);
            wk[j] = k < deg ? w : 0.0f;
            vk[j] = __shfl(nv, kc);
        }
        bf16x8 buf[4][2];
#pragma unroll
        for (int j = 0; j < 4; ++j) {
            const unsigned short* rp = u2ebf + (long)vk[j] * 64 + cl * 16;
            buf[j][0] = *(const bf16x8*)rp;
            buf[j][1] = *(const bf16x8*)(rp + 8);
        }
        float a[16];
#pragma unroll
        for (int j = 0; j < 16; ++j) a[j] = 0.f;
        float s = 0.f;
#pragma unroll
        for (int j = 0; j < 4; ++j) {
            s += wk[j];
            const unsigned* d0 = (const unsigned*)&buf[j][0];
            const unsigned* d1 = (const unsigned*)&buf[j][1];
#pragma unroll
            for (int tt = 0; tt < 4; ++tt) {
                a[2 * tt]         = fmaf(wk[j], __uint_as_float(d0[tt] << 16), a[2 * tt]);
                a[2 * tt + 1]     = fmaf(wk[j], __uint_as_float(d0[tt] & 0xFFFF0000u), a[2 * tt + 1]);
                a[8 + 2 * tt]     = fmaf(wk[j], __uint_as_float(d1[tt] << 16), a[8 + 2 * tt]);
                a[8 + 2 * tt + 1] = fmaf(wk[j], __uint_as_float(d1[tt] & 0xFFFF0000u), a[8 + 2 * tt + 1]);
            }
        }
        // residual for deg > 64 (statistically never at mean degree 32)
        for (int k = 64 + slot; k < deg; k += 16) {
            float w = ex[lo + k];
            int vi = neigh[lo + k];
            s += w;
            const unsigned short* rp = u2ebf + (long)vi * 64 + cl * 16;
            bf16x8 r0 = *(const bf16x8*)rp;
            bf16x8 r1 = *(const bf16x8*)(rp + 8);
            const unsigned* d0 = (const unsigned*)&r0;
            const unsigned* d1 = (const unsigned*)&r1;
#pragma unroll
            for (int tt = 0; tt < 4; ++tt) {
                a[2 * tt]         = fmaf(w, __uint_as_float(d0[tt] << 16), a[2 * tt]);
                a[2 * tt + 1]     = fmaf(w, __uint_as_float(d0[tt] & 0xFFFF0000u), a[2 * tt + 1]);
                a[8 + 2 * tt]     = fmaf(w, __uint_as_float(d1[tt] << 16), a[8 + 2 * tt]);
                a[8 + 2 * tt + 1] = fmaf(w, __uint_as_float(d1[tt] & 0xFFFF0000u), a[8 + 2 * tt + 1]);
            }
        }
#pragma unroll
        for (int msk = 4; msk <= 32; msk <<= 1) {
            s += __shfl_xor(s, msk);
#pragma unroll
            for (int j = 0; j < 16; ++j) a[j] += __shfl_xor(a[j], msk);
        }
        if (slot == 0) {
            float inv = 1.0f / fmaxf(s, 1e-9f);
            float* op = out + (long)n * 64 + cl * 16;
#pragma unroll
            for (int j = 0; j < 4; ++j) {
                float4 o = {a[4 * j] * inv, a[4 * j + 1] * inv,
                            a[4 * j + 2] * inv, a[4 * j + 3] * inv};
                *(float4*)(op + 4 * j) = o;
            }
        }
    } else {
        // fallback-tier path (f32 table), 8-slot structure
        const int slot = lane >> 3;
        const int cl = lane & 7;
        float a[8] = {0.f, 0.f, 0.f, 0.f, 0.f, 0.f, 0.f, 0.f};
        float s = 0.0f;
        for (int e = lo + slot; e < hi; e += 8) {
            float w = ex[e];
            int vi = neigh[e];
            s += w;
            const float* row = u2e + (long)vi * 64 + cl * 8;
            float4 v0 = *(const float4*)row;
            float4 v1 = *(const float4*)(row + 4);
            a[0] = fmaf(w, v0.x, a[0]); a[1] = fmaf(w, v0.y, a[1]);
            a[2] = fmaf(w, v0.z, a[2]); a[3] = fmaf(w, v0.w, a[3]);
            a[4] = fmaf(w, v1.x, a[4]); a[5] = fmaf(w, v1.y, a[5]);
            a[6] = fmaf(w, v1.z, a[6]); a[7] = fmaf(w, v1.w, a[7]);
        }
#pragma unroll
        for (int msk = 8; msk <= 32; msk <<= 1) {
            s += __shfl_xor(s, msk);
#pragma unroll
            for (int j = 0; j < 8; ++j) a[j] += __shfl_xor(a[j], msk);
        }
        if (slot == 0) {
            float inv = 1.0f / fmaxf(s, 1e-9f);
            float4 o0 = {a[0] * inv, a[1] * inv, a[2] * inv, a[3] * inv};
            float4 o1 = {a[4] * inv, a[5] * inv, a[6] * inv, a[7] * inv};
            float* op = out + (long)n * 64 + cl * 8;
            *(float4*)op = o0;
            *(float4*)(op + 4) = o1;
        }
    }
}

// ---------------- tier-3 fallback (tiny ws) -------------------------------------
__global__ void prep_bounds_k(const float* __restrict__ w1,
                              const float* __restrict__ w2,
                              const int* __restrict__ segs,
                              unsigned short* __restrict__ w1t,
                              unsigned short* __restrict__ w2t,
                              int* __restrict__ seg_off, int N, int E) {
    int t = threadIdx.x;
    if (blockIdx.x == 0) {
        for (int i = t; i < 128 * 64; i += 256) {
            int k = i >> 6, n = i & 63;
            w1t[n * 128 + k] = f2bf(w1[i]);
        }
        for (int i = t; i < 64 * 64; i += 256) {
            int k = i >> 6, n = i & 63;
            w2t[n * 64 + k] = f2bf(w2[i]);
        }
    } else {
        int idx = (blockIdx.x - 1) * 256 + t;
        if (idx > N) return;
        int l = 0, r = E;
        while (l < r) { int mid = (l + r) >> 1; if (segs[mid] < idx) l = mid + 1; else r = mid; }
        seg_off[idx] = l;
    }
}

__launch_bounds__(256)
__global__ void logits_fb_k(const int* __restrict__ nodes,
                            const int* __restrict__ neigh,
                            const int* __restrict__ segs,
                            const float* __restrict__ u2e,
                            const unsigned short* __restrict__ w1t,
                            const unsigned short* __restrict__ w2t,
                            const float* __restrict__ b1f, const float* __restrict__ b2f,
                            const float* __restrict__ w3f, const float* __restrict__ b3f,
                            float* __restrict__ ex, int E) {
    __shared__ __align__(16) unsigned short h1buf[4][16 * 72];
    const int wid = threadIdx.x >> 6;
    const int lane = threadIdx.x & 63;
    const int q = lane >> 4;
    const int m15 = lane & 15;
    const long base = ((long)blockIdx.x * 4 + wid) * 16;
    long ee0 = base + m15;
    int e = (int)(ee0 < E ? ee0 : (long)E - 1);
    int ni = neigh[e];
    int ctr = nodes[segs[e]];
    const float* eu = u2e + (long)ni * 64;
    const float* ur = u2e + (long)ctr * 64;
    bf16x8 a0 = cvt8(eu + q * 8), a1 = cvt8(eu + 32 + q * 8);
    bf16x8 a2 = cvt8(ur + q * 8), a3 = cvt8(ur + 32 + q * 8);
    f32x4 acc[4];
#pragma unroll
    for (int b = 0; b < 4; ++b) {
        float bvv = b1f[b * 16 + m15];
        acc[b] = (f32x4){bvv, bvv, bvv, bvv};
        const bf16x8* wrow = (const bf16x8*)(w1t + (b * 16 + m15) * 128);
        acc[b] = __builtin_amdgcn_mfma_f32_16x16x32_bf16(a0, wrow[0 + q], acc[b], 0, 0, 0);
        acc[b] = __builtin_amdgcn_mfma_f32_16x16x32_bf16(a1, wrow[4 + q], acc[b], 0, 0, 0);
        acc[b] = __builtin_amdgcn_mfma_f32_16x16x32_bf16(a2, wrow[8 + q], acc[b], 0, 0, 0);
        acc[b] = __builtin_amdgcn_mfma_f32_16x16x32_bf16(a3, wrow[12 + q], acc[b], 0, 0, 0);
    }
#pragma unroll
    for (int b = 0; b < 4; ++b)
#pragma unroll
        for (int r = 0; r < 4; ++r)
            h1buf[wid][(q * 4 + r) * 72 + b * 16 + m15] = f2bf(fmaxf(acc[b][r], 0.0f));
    const unsigned short* hrow = &h1buf[wid][m15 * 72];
    bf16x8 h0 = *(const bf16x8*)(hrow + q * 8);
    bf16x8 h1 = *(const bf16x8*)(hrow + 32 + q * 8);
    f32x4 acc2[4];
#pragma unroll
    for (int b = 0; b < 4; ++b) {
        float bvv = b2f[b * 16 + m15];
        acc2[b] = (f32x4){bvv, bvv, bvv, bvv};
        const bf16x8* wrow = (const bf16x8*)(w2t + (b * 16 + m15) * 64);
        acc2[b] = __builtin_amdgcn_mfma_f32_16x16x32_bf16(h0, wrow[0 + q], acc2[b], 0, 0, 0);
        acc2[b] = __builtin_amdgcn_mfma_f32_16x16x32_bf16(h1, wrow[4 + q], acc2[b], 0, 0, 0);
    }
    float b3v = b3f[0];
#pragma unroll
    for (int r = 0; r < 4; ++r) {
        float v = 0.0f;
#pragma unroll
        for (int b = 0; b < 4; ++b) v += fmaxf(acc2[b][r], 0.0f) * w3f[b * 16 + m15];
        v += __shfl_xor(v, 1);
        v += __shfl_xor(v, 2);
        v += __shfl_xor(v, 4);
        v += __shfl_xor(v, 8);
        long ee = base + q * 4 + r;
        if (m15 == r && ee < E) ex[ee] = __expf(v + b3v);
    }
}

extern "C" void kernel_launch(void* const* d_in, const int* in_sizes, int n_in,
                              void* d_out, int out_size, void* d_ws, size_t ws_size,
                              hipStream_t stream) {
    const int* nodes = (const int*)d_in[0];
    const int* neigh = (const int*)d_in[1];
    const int* segs  = (const int*)d_in[2];
    const float* u2e = (const float*)d_in[3];
    const float* w1  = (const float*)d_in[4];
    const float* b1  = (const float*)d_in[5];
    const float* w2  = (const float*)d_in[6];
    const float* b2  = (const float*)d_in[7];
    const float* w3  = (const float*)d_in[8];
    const float* b3  = (const float*)d_in[9];
    const int N = in_sizes[0];
    const int E = in_sizes[1];
    const long VD = in_sizes[3];
    const int V = (int)(VD / 64);

    char* ws = (char*)d_ws;
    size_t off = 0;
    auto alloc = [&](size_t bytes) { char* p = ws + off; off = (off + bytes + 255) & ~(size_t)255; return p; };
    float* ex = (float*)alloc((size_t)E * 4);
    int* seg_off = (int*)alloc((size_t)(N + 1) * 4);
    unsigned short* w1t = (unsigned short*)alloc(128 * 64 * 2);   // tier-3 only
    unsigned short* w2t = (unsigned short*)alloc(64 * 64 * 2);
    size_t need_min = off;
    unsigned short* Y = (unsigned short*)alloc((size_t)VD * 2);
    unsigned short* zb = (unsigned short*)alloc((size_t)N * 64 * 2);
    size_t need_t2 = off;
    unsigned short* u2ebf = (unsigned short*)alloc((size_t)VD * 2);
    size_t need_t1 = off;
    (void)need_min;

    float* out = (float*)d_out;

    const int ytiles = (V + 63) / 64;
    const int ztiles = (N + 63) / 64;
    const int yblk = ytiles < 640 ? ytiles : 640;
    const int zblk = ztiles < 160 ? ztiles : 160;
    const int bblocks = (N + 256) / 256;
    const int lblocks = ((E + 31) / 32 + 3) / 4;
    const int ablocks = (N + 3) / 4;

    if (ws_size >= need_t1) {
        conv_all_k<true><<<yblk + zblk + 1 + bblocks, 256, 0, stream>>>(
            u2e, nodes, segs, w1, w2, b1, u2ebf, Y, zb, w2t, seg_off, V, N, E,
            yblk, zblk, ytiles, ztiles);
        logits2_k<<<lblocks, 256, 0, stream>>>(neigh, segs, Y, zb, w2t, b2, w3, b3, ex, E);
        aggw_k<true><<<ablocks, 256, 0, stream>>>(seg_off, neigh, u2ebf, nullptr, ex, out, N);
    } else if (ws_size >= need_t2) {
        conv_all_k<false><<<yblk + zblk + 1 + bblocks, 256, 0, stream>>>(
            u2e, nodes, segs, w1, w2, b1, nullptr, Y, zb, w2t, seg_off, V, N, E,
            yblk, zblk, ytiles, ztiles);
        logits2_k<<<lblocks, 256, 0, stream>>>(neigh, segs, Y, zb, w2t, b2, w3, b3, ex, E);
        aggw_k<false><<<ablocks, 256, 0, stream>>>(seg_off, neigh, nullptr, u2e, ex, out, N);
    } else {
        const int pbblocks = 1 + (N + 256) / 256;
        prep_bounds_k<<<pbblocks, 256, 0, stream>>>(w1, w2, segs, w1t, w2t, seg_off, N, E);
        const int blocks1 = ((E + 15) / 16 + 3) / 4;
        logits_fb_k<<<blocks1, 256, 0, stream>>>(nodes, neigh, segs, u2e, w1t, w2t,
                                                 b1, b2, w3, b3, ex, E);
        aggw_k<false><<<ablocks, 256, 0, stream>>>(seg_off, neigh, nullptr, u2e, ex, out, N);
    }
}

// Round 5
// 149.189 us; speedup vs baseline: 1.0534x; 1.0534x over previous
//
#include <hip/hip_runtime.h>
#include <hip/hip_bf16.h>

typedef __attribute__((ext_vector_type(8))) short bf16x8;
typedef __attribute__((ext_vector_type(4))) float f32x4;

__device__ __forceinline__ unsigned short f2bf(float f) {
    unsigned x = __float_as_uint(f);
    unsigned r = (x + 0x7FFF + ((x >> 16) & 1)) >> 16;   // RNE
    return (unsigned short)r;
}
__device__ __forceinline__ bf16x8 cvt8(const float* __restrict__ p) {
    bf16x8 r;
#pragma unroll
    for (int j = 0; j < 8; ++j) r[j] = (short)f2bf(p[j]);
    return r;
}
__device__ __forceinline__ unsigned pack_relu_bf16(unsigned yv, unsigned zv) {
    float lo = fmaxf(__uint_as_float(yv << 16) + __uint_as_float(zv << 16), 0.0f);
    float hi = fmaxf(__uint_as_float(yv & 0xFFFF0000u) + __uint_as_float(zv & 0xFFFF0000u), 0.0f);
    __hip_bfloat162 p = __float22bfloat162_rn(float2{lo, hi});
    return *(unsigned*)&p;
}

// ---------------- kernel B (all-in-one prep): grid sections ----------------------
// T1 (tier-1): yu = interleaved [V][128] rows: cols 0-63 = Y (u2e@W1_top, bf16),
//              cols 64-127 = u2e row in bf16. Plus: zero d_out and den.
// !T1 (tier-2): separate Y [V][64], no u2e-bf16 writeback, seg_off binary search.
template <bool T1>
__launch_bounds__(256)
__global__ void conv_all_k(const float* __restrict__ u2e,
                           const int* __restrict__ nodes,
                           const int* __restrict__ segs,
                           const float* __restrict__ w1,
                           const float* __restrict__ w2,
                           const float* __restrict__ b1f,
                           unsigned short* __restrict__ yu,   // T1: [V][128]; !T1: Y [V][64]
                           unsigned short* __restrict__ z,
                           unsigned short* __restrict__ w2t,
                           int* __restrict__ seg_off,         // !T1 only
                           float* __restrict__ zout,          // T1 only: d_out to zero
                           float* __restrict__ den,           // T1 only: denom to zero
                           int V, int N, int E, int yblk, int zblk,
                           int ytiles, int ztiles) {
    __shared__ __align__(16) unsigned short w1l[64 * 72];
    const int bid = blockIdx.x;
    const int t = threadIdx.x;
    const int wid = t >> 6;
    const int lane = t & 63;
    const int q = lane >> 4;
    const int m15 = lane & 15;

    if (bid < yblk + zblk) {
        const bool isY = bid < yblk;
        const int kbase = isY ? 0 : 64;
        for (int u = t; u < 64 * 16; u += 256) {
            int k = u >> 4;
            int n4 = (u & 15) * 4;
            float4 v = *(const float4*)(w1 + (long)(kbase + k) * 64 + n4);
            w1l[(n4 + 0) * 72 + k] = f2bf(v.x);
            w1l[(n4 + 1) * 72 + k] = f2bf(v.y);
            w1l[(n4 + 2) * 72 + k] = f2bf(v.z);
            w1l[(n4 + 3) * 72 + k] = f2bf(v.w);
        }
        __syncthreads();

        bf16x8 wb0[4], wb1[4];
#pragma unroll
        for (int b = 0; b < 4; ++b) {
            const unsigned short* wr = w1l + (b * 16 + m15) * 72;
            wb0[b] = *(const bf16x8*)(wr + q * 8);
            wb1[b] = *(const bf16x8*)(wr + 32 + q * 8);
        }

        if (isY) {
            const int ystride = T1 ? 128 : 64;
            for (int tile = bid; tile < ytiles; tile += yblk) {
                const int wbase = tile * 64 + wid * 16;
                if (wbase >= V) continue;
                int row = min(wbase + m15, V - 1);
                const float* p = u2e + (long)row * 64;
                bf16x8 a0 = cvt8(p + q * 8);
                bf16x8 a1 = cvt8(p + 32 + q * 8);
                if (T1 && wbase + m15 < V) {
                    // u2e bf16 halves into cols 64..127 of the interleaved row
                    *(bf16x8*)(yu + (long)row * 128 + 64 + q * 8) = a0;
                    *(bf16x8*)(yu + (long)row * 128 + 96 + q * 8) = a1;
                }
                f32x4 acc[4];
#pragma unroll
                for (int b = 0; b < 4; ++b) {
                    acc[b] = (f32x4){0.f, 0.f, 0.f, 0.f};
                    acc[b] = __builtin_amdgcn_mfma_f32_16x16x32_bf16(a0, wb0[b], acc[b], 0, 0, 0);
                    acc[b] = __builtin_amdgcn_mfma_f32_16x16x32_bf16(a1, wb1[b], acc[b], 0, 0, 0);
                }
#pragma unroll
                for (int b = 0; b < 4; ++b)
#pragma unroll
                    for (int r = 0; r < 4; ++r) {
                        int rr = wbase + q * 4 + r;
                        if (rr < V) yu[(long)rr * ystride + b * 16 + m15] = f2bf(acc[b][r]);
                    }
            }
        } else {
            float b1v[4];
#pragma unroll
            for (int b = 0; b < 4; ++b) b1v[b] = b1f[b * 16 + m15];
            for (int tile = bid - yblk; tile < ztiles; tile += zblk) {
                const int wbase = tile * 64 + wid * 16;
                if (wbase >= N) continue;
                int nd = nodes[min(wbase + m15, N - 1)];
                const float* p = u2e + (long)nd * 64;
                bf16x8 a0 = cvt8(p + q * 8);
                bf16x8 a1 = cvt8(p + 32 + q * 8);
                f32x4 acc[4];
#pragma unroll
                for (int b = 0; b < 4; ++b) {
                    acc[b] = (f32x4){b1v[b], b1v[b], b1v[b], b1v[b]};
                    acc[b] = __builtin_amdgcn_mfma_f32_16x16x32_bf16(a0, wb0[b], acc[b], 0, 0, 0);
                    acc[b] = __builtin_amdgcn_mfma_f32_16x16x32_bf16(a1, wb1[b], acc[b], 0, 0, 0);
                }
#pragma unroll
                for (int b = 0; b < 4; ++b)
#pragma unroll
                    for (int r = 0; r < 4; ++r) {
                        int rr = wbase + q * 4 + r;
                        if (rr < N) z[(long)rr * 64 + b * 16 + m15] = f2bf(acc[b][r]);
                    }
            }
        }
    } else if (bid == yblk + zblk) {
        for (int i = t; i < 64 * 64; i += 256) {
            int k = i >> 6, n = i & 63;
            w2t[n * 64 + k] = f2bf(w2[i]);
        }
    } else {
        if (T1) {
            // zero d_out (N*64 f32) and den (N f32) via grid-stride float4 stores
            long zt = (long)(bid - yblk - zblk - 1) * 256 + t;
            long nth = (long)(gridDim.x - yblk - zblk - 1) * 256;
            f32x4 zz = (f32x4){0.f, 0.f, 0.f, 0.f};
            for (long i = zt; i < (long)N * 16; i += nth) ((f32x4*)zout)[i] = zz;
            for (long i = zt; i < (long)((N + 3) / 4); i += nth) ((f32x4*)den)[i] = zz;
        } else {
            int idx = (bid - yblk - zblk - 1) * 256 + t;
            if (idx > N) return;
            int l = 0, r = E;
            while (l < r) { int mid = (l + r) >> 1; if (segs[mid] < idx) l = mid + 1; else r = mid; }
            seg_off[idx] = l;
        }
    }
}

// ---------------- tier-1 fused: per-edge MLP + atomic weighted aggregation ------
// Edge-parallel, 32 edges/wave (2x16 groups), flat loads (no serial chain).
// Per edge ONE 256B interleaved yu row fetch covers both the logits MFMA operand
// (Y half) and the aggregation embedding (U half). ex never touches memory.
// Aggregation: in-wave reduce-scatter over the 16-lane m15 dimension -> lane
// (q,m15) holds the segment total for channel q*16+m15 = lane -> ONE 64-lane
// atomicAdd instruction per (group, node).
__launch_bounds__(256)
__global__ void fused_ea_k(const int* __restrict__ neigh,
                           const int* __restrict__ segs,
                           const unsigned short* __restrict__ yu,
                           const unsigned short* __restrict__ z,
                           const unsigned short* __restrict__ w2t,
                           const float* __restrict__ b2f,
                           const float* __restrict__ w3f,
                           const float* __restrict__ b3f,
                           float* __restrict__ outp,
                           float* __restrict__ den, int E) {
    const int wid = threadIdx.x >> 6;
    const int lane = threadIdx.x & 63;
    const int q = lane >> 4;
    const int m15 = lane & 15;
    const long base = ((long)blockIdx.x * 4 + wid) * 32;
    if (base >= E) return;

    int vi[2], sg[2];
    bool val[2];
#pragma unroll
    for (int g = 0; g < 2; ++g) {
        long e = base + g * 16 + m15;
        val[g] = e < E;
        int ec = (int)(val[g] ? e : (long)E - 1);
        vi[g] = neigh[ec];
        sg[g] = segs[ec];
    }
    // flat loads: Y half (MFMA A operand) + U half (aggregation) + z rows
    bf16x8 y0[2], y1[2], u0[2], u1[2], zz0[2], zz1[2];
#pragma unroll
    for (int g = 0; g < 2; ++g) {
        const unsigned short* r = yu + (long)vi[g] * 128;
        y0[g] = *(const bf16x8*)(r + q * 8);
        y1[g] = *(const bf16x8*)(r + 32 + q * 8);
        u0[g] = *(const bf16x8*)(r + 64 + q * 16);
        u1[g] = *(const bf16x8*)(r + 64 + q * 16 + 8);
        const unsigned short* zr = z + (long)sg[g] * 64;
        zz0[g] = *(const bf16x8*)(zr + q * 8);
        zz1[g] = *(const bf16x8*)(zr + 32 + q * 8);
    }

    float b2v[4], w3v[4];
#pragma unroll
    for (int b = 0; b < 4; ++b) {
        b2v[b] = b2f[b * 16 + m15];
        w3v[b] = w3f[b * 16 + m15];
    }
    const float b3v = b3f[0];

    f32x4 acc[2][4];
#pragma unroll
    for (int g = 0; g < 2; ++g) {
        bf16x8 h0, h1;
#pragma unroll
        for (int j = 0; j < 4; ++j) {
            ((unsigned*)&h0)[j] = pack_relu_bf16(((unsigned*)&y0[g])[j], ((unsigned*)&zz0[g])[j]);
            ((unsigned*)&h1)[j] = pack_relu_bf16(((unsigned*)&y1[g])[j], ((unsigned*)&zz1[g])[j]);
        }
#pragma unroll
        for (int b = 0; b < 4; ++b) {
            acc[g][b] = (f32x4){b2v[b], b2v[b], b2v[b], b2v[b]};
            const bf16x8* wrow = (const bf16x8*)(w2t + (b * 16 + m15) * 64);
            acc[g][b] = __builtin_amdgcn_mfma_f32_16x16x32_bf16(h0, wrow[0 + q], acc[g][b], 0, 0, 0);
            acc[g][b] = __builtin_amdgcn_mfma_f32_16x16x32_bf16(h1, wrow[4 + q], acc[g][b], 0, 0, 0);
        }
    }

#pragma unroll
    for (int g = 0; g < 2; ++g) {
        // logits -> ex (identical numerics to logits2_k)
        float ev[4];
#pragma unroll
        for (int r = 0; r < 4; ++r) {
            float v = 0.0f;
#pragma unroll
            for (int b = 0; b < 4; ++b) v += fmaxf(acc[g][b][r], 0.0f) * w3v[b];
            v += __shfl_xor(v, 1);
            v += __shfl_xor(v, 2);
            v += __shfl_xor(v, 4);
            v += __shfl_xor(v, 8);
            ev[r] = __expf(v + b3v);   // all 16 lanes of group q hold ex(edge q*4+r)
        }
        // lane (q,m15) exposes ex for edge q*4 + (m15&3); fetch own edge's ex
        int rsel = m15 & 3;
        float exval = rsel == 0 ? ev[0] : (rsel == 1 ? ev[1] : (rsel == 2 ? ev[2] : ev[3]));
        float exm = __shfl(exval, ((m15 >> 2) << 4) | (m15 & 3));
        if (!val[g]) exm = 0.0f;

        // unpack this edge's 16 channels (ch = q*16 + c)
        float uc[16];
        const unsigned* du0 = (const unsigned*)&u0[g];
        const unsigned* du1 = (const unsigned*)&u1[g];
#pragma unroll
        for (int tt = 0; tt < 4; ++tt) {
            uc[2 * tt]         = __uint_as_float(du0[tt] << 16);
            uc[2 * tt + 1]     = __uint_as_float(du0[tt] & 0xFFFF0000u);
            uc[8 + 2 * tt]     = __uint_as_float(du1[tt] << 16);
            uc[8 + 2 * tt + 1] = __uint_as_float(du1[tt] & 0xFFFF0000u);
        }

        const int ndlo = __shfl(sg[g], 0);
        const int ndhi = __shfl(sg[g], 15);
        for (int nd = ndlo; nd <= ndhi; ++nd) {
            float sel = (sg[g] == nd) ? exm : 0.0f;
            float cs[16];
#pragma unroll
            for (int c = 0; c < 16; ++c) cs[c] = sel * uc[c];
            // reduce-scatter over m15: round k keeps element-bit k = (m15>>k)&1
            float c8[8];
            {
                const bool b = m15 & 1;
#pragma unroll
                for (int i = 0; i < 8; ++i) {
                    float keep = b ? cs[2 * i + 1] : cs[2 * i];
                    float send = b ? cs[2 * i] : cs[2 * i + 1];
                    c8[i] = keep + __shfl_xor(send, 1);
                }
            }
            float c4[4];
            {
                const bool b = m15 & 2;
#pragma unroll
                for (int i = 0; i < 4; ++i) {
                    float keep = b ? c8[2 * i + 1] : c8[2 * i];
                    float send = b ? c8[2 * i] : c8[2 * i + 1];
                    c4[i] = keep + __shfl_xor(send, 2);
                }
            }
            float c2[2];
            {
                const bool b = m15 & 4;
#pragma unroll
                for (int i = 0; i < 2; ++i) {
                    float keep = b ? c4[2 * i + 1] : c4[2 * i];
                    float send = b ? c4[2 * i] : c4[2 * i + 1];
                    c2[i] = keep + __shfl_xor(send, 4);
                }
            }
            float tot;
            {
                const bool b = m15 & 8;
                float keep = b ? c2[1] : c2[0];
                float send = b ? c2[0] : c2[1];
                tot = keep + __shfl_xor(send, 8);
            }
            // lane (q,m15) holds segment total for channel q*16+m15 == lane
            atomicAdd(outp + (long)nd * 64 + lane, tot);
            float ds = sel;
            ds += __shfl_xor(ds, 1);
            ds += __shfl_xor(ds, 2);
            ds += __shfl_xor(ds, 4);
            ds += __shfl_xor(ds, 8);
            if (lane == 0) atomicAdd(den + nd, ds);
        }
    }
}

// ---------------- tier-1 finalize: divide by denominator ------------------------
__launch_bounds__(256)
__global__ void div_k(float* __restrict__ out, const float* __restrict__ den, int N) {
    int i = blockIdx.x * 256 + threadIdx.x;
    if (i >= N * 16) return;
    float inv = 1.0f / fmaxf(den[i >> 4], 1e-9f);
    f32x4* p = (f32x4*)out + i;
    f32x4 v = *p;
    v[0] *= inv; v[1] *= inv; v[2] *= inv; v[3] *= inv;
    *p = v;
}

// ---------------- kernel 1 (tier-2): per-edge MLP, 32 edges/wave ----------------
__launch_bounds__(256)
__global__ void logits2_k(const int* __restrict__ neigh,
                          const int* __restrict__ segs,
                          const unsigned short* __restrict__ Y,
                          const unsigned short* __restrict__ z,
                          const unsigned short* __restrict__ w2t,
                          const float* __restrict__ b2f,
                          const float* __restrict__ w3f, const float* __restrict__ b3f,
                          float* __restrict__ ex, int E) {
    const int wid = threadIdx.x >> 6;
    const int lane = threadIdx.x & 63;
    const int q = lane >> 4;
    const int m15 = lane & 15;
    const long base = ((long)blockIdx.x * 4 + wid) * 32;
    if (base >= E) return;

    int vi[2], sg[2];
#pragma unroll
    for (int g = 0; g < 2; ++g) {
        long e = base + g * 16 + m15;
        int ec = (int)(e < E ? e : (long)E - 1);
        vi[g] = neigh[ec];
        sg[g] = segs[ec];
    }
    bf16x8 y0[2], y1[2], zz0[2], zz1[2];
#pragma unroll
    for (int g = 0; g < 2; ++g) {
        const unsigned short* yr = Y + (long)vi[g] * 64;
        y0[g] = *(const bf16x8*)(yr + q * 8);
        y1[g] = *(const bf16x8*)(yr + 32 + q * 8);
        const unsigned short* zr = z + (long)sg[g] * 64;
        zz0[g] = *(const bf16x8*)(zr + q * 8);
        zz1[g] = *(const bf16x8*)(zr + 32 + q * 8);
    }

    float b2v[4], w3v[4];
#pragma unroll
    for (int b = 0; b < 4; ++b) {
        b2v[b] = b2f[b * 16 + m15];
        w3v[b] = w3f[b * 16 + m15];
    }

    f32x4 acc[2][4];
#pragma unroll
    for (int g = 0; g < 2; ++g) {
        bf16x8 h0, h1;
#pragma unroll
        for (int j = 0; j < 4; ++j) {
            ((unsigned*)&h0)[j] = pack_relu_bf16(((unsigned*)&y0[g])[j], ((unsigned*)&zz0[g])[j]);
            ((unsigned*)&h1)[j] = pack_relu_bf16(((unsigned*)&y1[g])[j], ((unsigned*)&zz1[g])[j]);
        }
#pragma unroll
        for (int b = 0; b < 4; ++b) {
            acc[g][b] = (f32x4){b2v[b], b2v[b], b2v[b], b2v[b]};
            const bf16x8* wrow = (const bf16x8*)(w2t + (b * 16 + m15) * 64);
            acc[g][b] = __builtin_amdgcn_mfma_f32_16x16x32_bf16(h0, wrow[0 + q], acc[g][b], 0, 0, 0);
            acc[g][b] = __builtin_amdgcn_mfma_f32_16x16x32_bf16(h1, wrow[4 + q], acc[g][b], 0, 0, 0);
        }
    }

    const float b3v = b3f[0];
#pragma unroll
    for (int g = 0; g < 2; ++g)
#pragma unroll
        for (int r = 0; r < 4; ++r) {
            float v = 0.0f;
#pragma unroll
            for (int b = 0; b < 4; ++b) v += fmaxf(acc[g][b][r], 0.0f) * w3v[b];
            v += __shfl_xor(v, 1);
            v += __shfl_xor(v, 2);
            v += __shfl_xor(v, 4);
            v += __shfl_xor(v, 8);
            long ee = base + g * 16 + q * 4 + r;
            if (m15 == r && ee < E) ex[ee] = __expf(v + b3v);
        }
}

// ---------------- kernel 2 (tier-2/3): wave-per-node weighted segment sum -------
__launch_bounds__(256)
__global__ void aggw_f32_k(const int* __restrict__ seg_off,
                           const int* __restrict__ neigh,
                           const float* __restrict__ u2e,
                           const float* __restrict__ ex,
                           float* __restrict__ out, int N) {
    const int wid = threadIdx.x >> 6;
    const int lane = threadIdx.x & 63;
    const int n = blockIdx.x * 4 + wid;
    if (n >= N) return;
    const int lo = seg_off[n];
    const int hi = seg_off[n + 1];
    const int slot = lane >> 3;
    const int cl = lane & 7;

    float a[8] = {0.f, 0.f, 0.f, 0.f, 0.f, 0.f, 0.f, 0.f};
    float s = 0.0f;

    for (int e = lo + slot; e < hi; e += 8) {
        float w = ex[e];
        int vi = neigh[e];
        s += w;
        const float* row = u2e + (long)vi * 64 + cl * 8;
        float4 v0 = *(const float4*)row;
        float4 v1 = *(const float4*)(row + 4);
        a[0] = fmaf(w, v0.x, a[0]); a[1] = fmaf(w, v0.y, a[1]);
        a[2] = fmaf(w, v0.z, a[2]); a[3] = fmaf(w, v0.w, a[3]);
        a[4] = fmaf(w, v1.x, a[4]); a[5] = fmaf(w, v1.y, a[5]);
        a[6] = fmaf(w, v1.z, a[6]); a[7] = fmaf(w, v1.w, a[7]);
    }
#pragma unroll
    for (int msk = 8; msk <= 32; msk <<= 1) {
        s += __shfl_xor(s, msk);
#pragma unroll
        for (int j = 0; j < 8; ++j) a[j] += __shfl_xor(a[j], msk);
    }
    if (slot == 0) {
        float inv = 1.0f / fmaxf(s, 1e-9f);
        float4 o0 = {a[0] * inv, a[1] * inv, a[2] * inv, a[3] * inv};
        float4 o1 = {a[4] * inv, a[5] * inv, a[6] * inv, a[7] * inv};
        float* op = out + (long)n * 64 + cl * 8;
        *(float4*)op = o0;
        *(float4*)(op + 4) = o1;
    }
}

// ---------------- tier-3 fallback (tiny ws) -------------------------------------
__global__ void prep_bounds_k(const float* __restrict__ w1,
                              const float* __restrict__ w2,
                              const int* __restrict__ segs,
                              unsigned short* __restrict__ w1t,
                              unsigned short* __restrict__ w2t,
                              int* __restrict__ seg_off, int N, int E) {
    int t = threadIdx.x;
    if (blockIdx.x == 0) {
        for (int i = t; i < 128 * 64; i += 256) {
            int k = i >> 6, n = i & 63;
            w1t[n * 128 + k] = f2bf(w1[i]);
        }
        for (int i = t; i < 64 * 64; i += 256) {
            int k = i >> 6, n = i & 63;
            w2t[n * 64 + k] = f2bf(w2[i]);
        }
    } else {
        int idx = (blockIdx.x - 1) * 256 + t;
        if (idx > N) return;
        int l = 0, r = E;
        while (l < r) { int mid = (l + r) >> 1; if (segs[mid] < idx) l = mid + 1; else r = mid; }
        seg_off[idx] = l;
    }
}

__launch_bounds__(256)
__global__ void logits_fb_k(const int* __restrict__ nodes,
                            const int* __restrict__ neigh,
                            const int* __restrict__ segs,
                            const float* __restrict__ u2e,
                            const unsigned short* __restrict__ w1t,
                            const unsigned short* __restrict__ w2t,
                            const float* __restrict__ b1f, const float* __restrict__ b2f,
                            const float* __restrict__ w3f, const float* __restrict__ b3f,
                            float* __restrict__ ex, int E) {
    __shared__ __align__(16) unsigned short h1buf[4][16 * 72];
    const int wid = threadIdx.x >> 6;
    const int lane = threadIdx.x & 63;
    const int q = lane >> 4;
    const int m15 = lane & 15;
    const long base = ((long)blockIdx.x * 4 + wid) * 16;
    long ee0 = base + m15;
    int e = (int)(ee0 < E ? ee0 : (long)E - 1);
    int ni = neigh[e];
    int ctr = nodes[segs[e]];
    const float* eu = u2e + (long)ni * 64;
    const float* ur = u2e + (long)ctr * 64;
    bf16x8 a0 = cvt8(eu + q * 8), a1 = cvt8(eu + 32 + q * 8);
    bf16x8 a2 = cvt8(ur + q * 8), a3 = cvt8(ur + 32 + q * 8);
    f32x4 acc[4];
#pragma unroll
    for (int b = 0; b < 4; ++b) {
        float bvv = b1f[b * 16 + m15];
        acc[b] = (f32x4){bvv, bvv, bvv, bvv};
        const bf16x8* wrow = (const bf16x8*)(w1t + (b * 16 + m15) * 128);
        acc[b] = __builtin_amdgcn_mfma_f32_16x16x32_bf16(a0, wrow[0 + q], acc[b], 0, 0, 0);
        acc[b] = __builtin_amdgcn_mfma_f32_16x16x32_bf16(a1, wrow[4 + q], acc[b], 0, 0, 0);
        acc[b] = __builtin_amdgcn_mfma_f32_16x16x32_bf16(a2, wrow[8 + q], acc[b], 0, 0, 0);
        acc[b] = __builtin_amdgcn_mfma_f32_16x16x32_bf16(a3, wrow[12 + q], acc[b], 0, 0, 0);
    }
#pragma unroll
    for (int b = 0; b < 4; ++b)
#pragma unroll
        for (int r = 0; r < 4; ++r)
            h1buf[wid][(q * 4 + r) * 72 + b * 16 + m15] = f2bf(fmaxf(acc[b][r], 0.0f));
    const unsigned short* hrow = &h1buf[wid][m15 * 72];
    bf16x8 h0 = *(const bf16x8*)(hrow + q * 8);
    bf16x8 h1 = *(const bf16x8*)(hrow + 32 + q * 8);
    f32x4 acc2[4];
#pragma unroll
    for (int b = 0; b < 4; ++b) {
        float bvv = b2f[b * 16 + m15];
        acc2[b] = (f32x4){bvv, bvv, bvv, bvv};
        const bf16x8* wrow = (const bf16x8*)(w2t + (b * 16 + m15) * 64);
        acc2[b] = __builtin_amdgcn_mfma_f32_16x16x32_bf16(h0, wrow[0 + q], acc2[b], 0, 0, 0);
        acc2[b] = __builtin_amdgcn_mfma_f32_16x16x32_bf16(h1, wrow[4 + q], acc2[b], 0, 0, 0);
    }
    float b3v = b3f[0];
#pragma unroll
    for (int r = 0; r < 4; ++r) {
        float v = 0.0f;
#pragma unroll
        for (int b = 0; b < 4; ++b) v += fmaxf(acc2[b][r], 0.0f) * w3f[b * 16 + m15];
        v += __shfl_xor(v, 1);
        v += __shfl_xor(v, 2);
        v += __shfl_xor(v, 4);
        v += __shfl_xor(v, 8);
        long ee = base + q * 4 + r;
        if (m15 == r && ee < E) ex[ee] = __expf(v + b3v);
    }
}

extern "C" void kernel_launch(void* const* d_in, const int* in_sizes, int n_in,
                              void* d_out, int out_size, void* d_ws, size_t ws_size,
                              hipStream_t stream) {
    const int* nodes = (const int*)d_in[0];
    const int* neigh = (const int*)d_in[1];
    const int* segs  = (const int*)d_in[2];
    const float* u2e = (const float*)d_in[3];
    const float* w1  = (const float*)d_in[4];
    const float* b1  = (const float*)d_in[5];
    const float* w2  = (const float*)d_in[6];
    const float* b2  = (const float*)d_in[7];
    const float* w3  = (const float*)d_in[8];
    const float* b3  = (const float*)d_in[9];
    const int N = in_sizes[0];
    const int E = in_sizes[1];
    const long VD = in_sizes[3];
    const int V = (int)(VD / 64);

    char* ws = (char*)d_ws;
    size_t off = 0;
    auto alloc = [&](size_t bytes) { char* p = ws + off; off = (off + bytes + 255) & ~(size_t)255; return p; };
    float* ex = (float*)alloc((size_t)E * 4);
    int* seg_off = (int*)alloc((size_t)(N + 1) * 4);
    unsigned short* w1t = (unsigned short*)alloc(128 * 64 * 2);   // tier-3 only
    unsigned short* w2t = (unsigned short*)alloc(64 * 64 * 2);
    size_t need_min = off;
    unsigned short* Y = (unsigned short*)alloc((size_t)VD * 2);
    unsigned short* zb = (unsigned short*)alloc((size_t)N * 64 * 2);
    size_t need_t2 = off;
    unsigned short* yu = (unsigned short*)alloc((size_t)VD * 4);  // interleaved [V][128]
    float* den = (float*)alloc((size_t)N * 4);
    size_t need_t1 = off;
    (void)need_min;

    float* out = (float*)d_out;

    const int ytiles = (V + 63) / 64;
    const int ztiles = (N + 63) / 64;
    const int yblk = ytiles < 640 ? ytiles : 640;
    const int zblk = ztiles < 160 ? ztiles : 160;
    const int bblocks = (N + 256) / 256;
    const int lblocks = ((E + 31) / 32 + 3) / 4;
    const int ablocks = (N + 3) / 4;
    const int ZBLK = 128;

    if (ws_size >= need_t1) {
        conv_all_k<true><<<yblk + zblk + 1 + ZBLK, 256, 0, stream>>>(
            u2e, nodes, segs, w1, w2, b1, yu, zb, w2t, nullptr, out, den,
            V, N, E, yblk, zblk, ytiles, ztiles);
        fused_ea_k<<<lblocks, 256, 0, stream>>>(
            neigh, segs, yu, zb, w2t, b2, w3, b3, out, den, E);
        div_k<<<(N * 16 + 255) / 256, 256, 0, stream>>>(out, den, N);
    } else if (ws_size >= need_t2) {
        conv_all_k<false><<<yblk + zblk + 1 + bblocks, 256, 0, stream>>>(
            u2e, nodes, segs, w1, w2, b1, Y, zb, w2t, seg_off, nullptr, nullptr,
            V, N, E, yblk, zblk, ytiles, ztiles);
        logits2_k<<<lblocks, 256, 0, stream>>>(neigh, segs, Y, zb, w2t, b2, w3, b3, ex, E);
        aggw_f32_k<<<ablocks, 256, 0, stream>>>(seg_off, neigh, u2e, ex, out, N);
    } else {
        const int pbblocks = 1 + (N + 256) / 256;
        prep_bounds_k<<<pbblocks, 256, 0, stream>>>(w1, w2, segs, w1t, w2t, seg_off, N, E);
        const int blocks1 = ((E + 15) / 16 + 3) / 4;
        logits_fb_k<<<blocks1, 256, 0, stream>>>(nodes, neigh, segs, u2e, w1t, w2t,
                                                 b1, b2, w3, b3, ex, E);
        aggw_f32_k<<<ablocks, 256, 0, stream>>>(seg_off, neigh, nullptr /*unused*/ == nullptr ? u2e : u2e, ex, out, N);
    }
}

// Round 6
// 147.398 us; speedup vs baseline: 1.0662x; 1.0122x over previous
//
#include <hip/hip_runtime.h>
#include <hip/hip_bf16.h>

typedef __attribute__((ext_vector_type(8))) short bf16x8;
typedef __attribute__((ext_vector_type(4))) float f32x4;

__device__ __forceinline__ unsigned short f2bf(float f) {
    unsigned x = __float_as_uint(f);
    unsigned r = (x + 0x7FFF + ((x >> 16) & 1)) >> 16;   // RNE
    return (unsigned short)r;
}
__device__ __forceinline__ bf16x8 cvt8(const float* __restrict__ p) {
    bf16x8 r;
#pragma unroll
    for (int j = 0; j < 8; ++j) r[j] = (short)f2bf(p[j]);
    return r;
}
__device__ __forceinline__ unsigned pack_relu_bf16(unsigned yv, unsigned zv) {
    float lo = fmaxf(__uint_as_float(yv << 16) + __uint_as_float(zv << 16), 0.0f);
    float hi = fmaxf(__uint_as_float(yv & 0xFFFF0000u) + __uint_as_float(zv & 0xFFFF0000u), 0.0f);
    __hip_bfloat162 p = __float22bfloat162_rn(float2{lo, hi});
    return *(unsigned*)&p;
}

// ---------------- kernel B (all-in-one prep): grid sections ----------------------
// T1: Y[V][64] = u2e@W1_top (bf16), u2ebf[V][64] = u2e in bf16, z, w2t; tail
//     sections zero d_out and den (needed by the atomic aggregation).
// !T1 (tier-2): Y + z + w2t + seg_off binary search (no u2ebf/zero).
template <bool T1>
__launch_bounds__(256)
__global__ void conv_all_k(const float* __restrict__ u2e,
                           const int* __restrict__ nodes,
                           const int* __restrict__ segs,
                           const float* __restrict__ w1,
                           const float* __restrict__ w2,
                           const float* __restrict__ b1f,
                           unsigned short* __restrict__ Y,
                           unsigned short* __restrict__ u2ebf,  // T1 only
                           unsigned short* __restrict__ z,
                           unsigned short* __restrict__ w2t,
                           int* __restrict__ seg_off,           // !T1 only
                           float* __restrict__ zout,            // T1 only
                           float* __restrict__ den,             // T1 only
                           int V, int N, int E, int yblk, int zblk,
                           int ytiles, int ztiles) {
    __shared__ __align__(16) unsigned short w1l[64 * 72];
    const int bid = blockIdx.x;
    const int t = threadIdx.x;
    const int wid = t >> 6;
    const int lane = t & 63;
    const int q = lane >> 4;
    const int m15 = lane & 15;

    if (bid < yblk + zblk) {
        const bool isY = bid < yblk;
        const int kbase = isY ? 0 : 64;
        for (int u = t; u < 64 * 16; u += 256) {
            int k = u >> 4;
            int n4 = (u & 15) * 4;
            float4 v = *(const float4*)(w1 + (long)(kbase + k) * 64 + n4);
            w1l[(n4 + 0) * 72 + k] = f2bf(v.x);
            w1l[(n4 + 1) * 72 + k] = f2bf(v.y);
            w1l[(n4 + 2) * 72 + k] = f2bf(v.z);
            w1l[(n4 + 3) * 72 + k] = f2bf(v.w);
        }
        __syncthreads();

        bf16x8 wb0[4], wb1[4];
#pragma unroll
        for (int b = 0; b < 4; ++b) {
            const unsigned short* wr = w1l + (b * 16 + m15) * 72;
            wb0[b] = *(const bf16x8*)(wr + q * 8);
            wb1[b] = *(const bf16x8*)(wr + 32 + q * 8);
        }

        if (isY) {
            for (int tile = bid; tile < ytiles; tile += yblk) {
                const int wbase = tile * 64 + wid * 16;
                if (wbase >= V) continue;
                int row = min(wbase + m15, V - 1);
                const float* p = u2e + (long)row * 64;
                bf16x8 a0 = cvt8(p + q * 8);
                bf16x8 a1 = cvt8(p + 32 + q * 8);
                if (T1 && wbase + m15 < V) {
                    *(bf16x8*)(u2ebf + (long)row * 64 + q * 8) = a0;
                    *(bf16x8*)(u2ebf + (long)row * 64 + 32 + q * 8) = a1;
                }
                f32x4 acc[4];
#pragma unroll
                for (int b = 0; b < 4; ++b) {
                    acc[b] = (f32x4){0.f, 0.f, 0.f, 0.f};
                    acc[b] = __builtin_amdgcn_mfma_f32_16x16x32_bf16(a0, wb0[b], acc[b], 0, 0, 0);
                    acc[b] = __builtin_amdgcn_mfma_f32_16x16x32_bf16(a1, wb1[b], acc[b], 0, 0, 0);
                }
#pragma unroll
                for (int b = 0; b < 4; ++b)
#pragma unroll
                    for (int r = 0; r < 4; ++r) {
                        int rr = wbase + q * 4 + r;
                        if (rr < V) Y[(long)rr * 64 + b * 16 + m15] = f2bf(acc[b][r]);
                    }
            }
        } else {
            float b1v[4];
#pragma unroll
            for (int b = 0; b < 4; ++b) b1v[b] = b1f[b * 16 + m15];
            for (int tile = bid - yblk; tile < ztiles; tile += zblk) {
                const int wbase = tile * 64 + wid * 16;
                if (wbase >= N) continue;
                int nd = nodes[min(wbase + m15, N - 1)];
                const float* p = u2e + (long)nd * 64;
                bf16x8 a0 = cvt8(p + q * 8);
                bf16x8 a1 = cvt8(p + 32 + q * 8);
                f32x4 acc[4];
#pragma unroll
                for (int b = 0; b < 4; ++b) {
                    acc[b] = (f32x4){b1v[b], b1v[b], b1v[b], b1v[b]};
                    acc[b] = __builtin_amdgcn_mfma_f32_16x16x32_bf16(a0, wb0[b], acc[b], 0, 0, 0);
                    acc[b] = __builtin_amdgcn_mfma_f32_16x16x32_bf16(a1, wb1[b], acc[b], 0, 0, 0);
                }
#pragma unroll
                for (int b = 0; b < 4; ++b)
#pragma unroll
                    for (int r = 0; r < 4; ++r) {
                        int rr = wbase + q * 4 + r;
                        if (rr < N) z[(long)rr * 64 + b * 16 + m15] = f2bf(acc[b][r]);
                    }
            }
        }
    } else if (bid == yblk + zblk) {
        for (int i = t; i < 64 * 64; i += 256) {
            int k = i >> 6, n = i & 63;
            w2t[n * 64 + k] = f2bf(w2[i]);
        }
    } else {
        if (T1) {
            long zt = (long)(bid - yblk - zblk - 1) * 256 + t;
            long nth = (long)(gridDim.x - yblk - zblk - 1) * 256;
            f32x4 zz = (f32x4){0.f, 0.f, 0.f, 0.f};
            for (long i = zt; i < (long)N * 16; i += nth) ((f32x4*)zout)[i] = zz;
            for (long i = zt; i < (long)((N + 3) / 4); i += nth) ((f32x4*)den)[i] = zz;
        } else {
            int idx = (bid - yblk - zblk - 1) * 256 + t;
            if (idx > N) return;
            int l = 0, r = E;
            while (l < r) { int mid = (l + r) >> 1; if (segs[mid] < idx) l = mid + 1; else r = mid; }
            seg_off[idx] = l;
        }
    }
}

// ---------------- tier-1 fused: per-edge MLP + scalar-broadcast aggregation -----
// Phase 1 (unchanged numerics): 32 edges/wave, MFMA logits -> per-edge ex.
// Phase 2: lane = channel. Edges are node-sorted, so the wave's 32 edges form a
// contiguous node-run. Per edge: readlane(vi,sg,ex) -> SGPR broadcast; each lane
// grabs u2ebf[vi*64+lane] (one coalesced 128B row per edge, issued EARLY so the
// 32 loads fly under the MFMA phase); acc = fmaf(ex, u, acc). Wave-uniform node
// boundary -> flush via one 64-lane atomicAdd + one den atomic. No cross-lane
// reduction at all in aggregation.
__launch_bounds__(256)
__global__ void fused_ea_k(const int* __restrict__ neigh,
                           const int* __restrict__ segs,
                           const unsigned short* __restrict__ Y,
                           const unsigned short* __restrict__ z,
                           const unsigned short* __restrict__ u2ebf,
                           const unsigned short* __restrict__ w2t,
                           const float* __restrict__ b2f,
                           const float* __restrict__ w3f,
                           const float* __restrict__ b3f,
                           float* __restrict__ outp,
                           float* __restrict__ den, int E) {
    const int wid = threadIdx.x >> 6;
    const int lane = threadIdx.x & 63;
    const int q = lane >> 4;
    const int m15 = lane & 15;
    const long base = ((long)blockIdx.x * 4 + wid) * 32;
    if (base >= E) return;

    int vi[2], sg[2];
    bool val[2];
#pragma unroll
    for (int g = 0; g < 2; ++g) {
        long e = base + g * 16 + m15;
        val[g] = e < E;
        int ec = (int)(val[g] ? e : (long)E - 1);
        vi[g] = neigh[ec];
        sg[g] = segs[ec];
    }

    // issue all 32 aggregation row-loads NOW (overlap with MFMA phase)
    unsigned short uv[2][16];
#pragma unroll
    for (int g = 0; g < 2; ++g)
#pragma unroll
        for (int j = 0; j < 16; ++j) {
            int svi = __builtin_amdgcn_readlane(vi[g], j);
            uv[g][j] = u2ebf[((long)svi << 6) + lane];
        }

    bf16x8 y0[2], y1[2], zz0[2], zz1[2];
#pragma unroll
    for (int g = 0; g < 2; ++g) {
        const unsigned short* yr = Y + (long)vi[g] * 64;
        y0[g] = *(const bf16x8*)(yr + q * 8);
        y1[g] = *(const bf16x8*)(yr + 32 + q * 8);
        const unsigned short* zr = z + (long)sg[g] * 64;
        zz0[g] = *(const bf16x8*)(zr + q * 8);
        zz1[g] = *(const bf16x8*)(zr + 32 + q * 8);
    }

    float b2v[4], w3v[4];
#pragma unroll
    for (int b = 0; b < 4; ++b) {
        b2v[b] = b2f[b * 16 + m15];
        w3v[b] = w3f[b * 16 + m15];
    }
    const float b3v = b3f[0];

    f32x4 acc[2][4];
#pragma unroll
    for (int g = 0; g < 2; ++g) {
        bf16x8 h0, h1;
#pragma unroll
        for (int j = 0; j < 4; ++j) {
            ((unsigned*)&h0)[j] = pack_relu_bf16(((unsigned*)&y0[g])[j], ((unsigned*)&zz0[g])[j]);
            ((unsigned*)&h1)[j] = pack_relu_bf16(((unsigned*)&y1[g])[j], ((unsigned*)&zz1[g])[j]);
        }
#pragma unroll
        for (int b = 0; b < 4; ++b) {
            acc[g][b] = (f32x4){b2v[b], b2v[b], b2v[b], b2v[b]};
            const bf16x8* wrow = (const bf16x8*)(w2t + (b * 16 + m15) * 64);
            acc[g][b] = __builtin_amdgcn_mfma_f32_16x16x32_bf16(h0, wrow[0 + q], acc[g][b], 0, 0, 0);
            acc[g][b] = __builtin_amdgcn_mfma_f32_16x16x32_bf16(h1, wrow[4 + q], acc[g][b], 0, 0, 0);
        }
    }

    float exm[2];
#pragma unroll
    for (int g = 0; g < 2; ++g) {
        float ev[4];
#pragma unroll
        for (int r = 0; r < 4; ++r) {
            float v = 0.0f;
#pragma unroll
            for (int b = 0; b < 4; ++b) v += fmaxf(acc[g][b][r], 0.0f) * w3v[b];
            v += __shfl_xor(v, 1);
            v += __shfl_xor(v, 2);
            v += __shfl_xor(v, 4);
            v += __shfl_xor(v, 8);
            ev[r] = __expf(v + b3v);
        }
        int rsel = m15 & 3;
        float exval = rsel == 0 ? ev[0] : (rsel == 1 ? ev[1] : (rsel == 2 ? ev[2] : ev[3]));
        float em = __shfl(exval, ((m15 >> 2) << 4) | (m15 & 3));
        exm[g] = val[g] ? em : 0.0f;
    }

    // ---- phase 2: channel-parallel accumulation with boundary flush ----
    float a = 0.0f;     // this lane's channel accumulator
    float ds = 0.0f;    // wave-uniform denominator accumulator
    int cur = __builtin_amdgcn_readlane(sg[0], 0);
#pragma unroll
    for (int g = 0; g < 2; ++g)
#pragma unroll
        for (int j = 0; j < 16; ++j) {
            int ssg = __builtin_amdgcn_readlane(sg[g], j);
            float sex = __uint_as_float(
                (unsigned)__builtin_amdgcn_readlane(__float_as_uint(exm[g]), j));
            if (ssg != cur) {   // wave-uniform branch (sorted segs)
                atomicAdd(outp + (long)cur * 64 + lane, a);
                if (lane == 0) atomicAdd(den + cur, ds);
                a = 0.0f; ds = 0.0f; cur = ssg;
            }
            a = fmaf(sex, __uint_as_float((unsigned)uv[g][j] << 16), a);
            ds += sex;
        }
    atomicAdd(outp + (long)cur * 64 + lane, a);
    if (lane == 0) atomicAdd(den + cur, ds);
}

// ---------------- tier-1 finalize: divide by denominator ------------------------
__launch_bounds__(256)
__global__ void div_k(float* __restrict__ out, const float* __restrict__ den, int N) {
    int i = blockIdx.x * 256 + threadIdx.x;
    if (i >= N * 16) return;
    float inv = 1.0f / fmaxf(den[i >> 4], 1e-9f);
    f32x4* p = (f32x4*)out + i;
    f32x4 v = *p;
    v[0] *= inv; v[1] *= inv; v[2] *= inv; v[3] *= inv;
    *p = v;
}

// ---------------- kernel 1 (tier-2): per-edge MLP, 32 edges/wave ----------------
__launch_bounds__(256)
__global__ void logits2_k(const int* __restrict__ neigh,
                          const int* __restrict__ segs,
                          const unsigned short* __restrict__ Y,
                          const unsigned short* __restrict__ z,
                          const unsigned short* __restrict__ w2t,
                          const float* __restrict__ b2f,
                          const float* __restrict__ w3f, const float* __restrict__ b3f,
                          float* __restrict__ ex, int E) {
    const int wid = threadIdx.x >> 6;
    const int lane = threadIdx.x & 63;
    const int q = lane >> 4;
    const int m15 = lane & 15;
    const long base = ((long)blockIdx.x * 4 + wid) * 32;
    if (base >= E) return;

    int vi[2], sg[2];
#pragma unroll
    for (int g = 0; g < 2; ++g) {
        long e = base + g * 16 + m15;
        int ec = (int)(e < E ? e : (long)E - 1);
        vi[g] = neigh[ec];
        sg[g] = segs[ec];
    }
    bf16x8 y0[2], y1[2], zz0[2], zz1[2];
#pragma unroll
    for (int g = 0; g < 2; ++g) {
        const unsigned short* yr = Y + (long)vi[g] * 64;
        y0[g] = *(const bf16x8*)(yr + q * 8);
        y1[g] = *(const bf16x8*)(yr + 32 + q * 8);
        const unsigned short* zr = z + (long)sg[g] * 64;
        zz0[g] = *(const bf16x8*)(zr + q * 8);
        zz1[g] = *(const bf16x8*)(zr + 32 + q * 8);
    }

    float b2v[4], w3v[4];
#pragma unroll
    for (int b = 0; b < 4; ++b) {
        b2v[b] = b2f[b * 16 + m15];
        w3v[b] = w3f[b * 16 + m15];
    }

    f32x4 acc[2][4];
#pragma unroll
    for (int g = 0; g < 2; ++g) {
        bf16x8 h0, h1;
#pragma unroll
        for (int j = 0; j < 4; ++j) {
            ((unsigned*)&h0)[j] = pack_relu_bf16(((unsigned*)&y0[g])[j], ((unsigned*)&zz0[g])[j]);
            ((unsigned*)&h1)[j] = pack_relu_bf16(((unsigned*)&y1[g])[j], ((unsigned*)&zz1[g])[j]);
        }
#pragma unroll
        for (int b = 0; b < 4; ++b) {
            acc[g][b] = (f32x4){b2v[b], b2v[b], b2v[b], b2v[b]};
            const bf16x8* wrow = (const bf16x8*)(w2t + (b * 16 + m15) * 64);
            acc[g][b] = __builtin_amdgcn_mfma_f32_16x16x32_bf16(h0, wrow[0 + q], acc[g][b], 0, 0, 0);
            acc[g][b] = __builtin_amdgcn_mfma_f32_16x16x32_bf16(h1, wrow[4 + q], acc[g][b], 0, 0, 0);
        }
    }

    const float b3v = b3f[0];
#pragma unroll
    for (int g = 0; g < 2; ++g)
#pragma unroll
        for (int r = 0; r < 4; ++r) {
            float v = 0.0f;
#pragma unroll
            for (int b = 0; b < 4; ++b) v += fmaxf(acc[g][b][r], 0.0f) * w3v[b];
            v += __shfl_xor(v, 1);
            v += __shfl_xor(v, 2);
            v += __shfl_xor(v, 4);
            v += __shfl_xor(v, 8);
            long ee = base + g * 16 + q * 4 + r;
            if (m15 == r && ee < E) ex[ee] = __expf(v + b3v);
        }
}

// ---------------- kernel 2 (tier-2/3): wave-per-node weighted segment sum -------
__launch_bounds__(256)
__global__ void aggw_f32_k(const int* __restrict__ seg_off,
                           const int* __restrict__ neigh,
                           const float* __restrict__ u2e,
                           const float* __restrict__ ex,
                           float* __restrict__ out, int N) {
    const int wid = threadIdx.x >> 6;
    const int lane = threadIdx.x & 63;
    const int n = blockIdx.x * 4 + wid;
    if (n >= N) return;
    const int lo = seg_off[n];
    const int hi = seg_off[n + 1];
    const int slot = lane >> 3;
    const int cl = lane & 7;

    float a[8] = {0.f, 0.f, 0.f, 0.f, 0.f, 0.f, 0.f, 0.f};
    float s = 0.0f;

    for (int e = lo + slot; e < hi; e += 8) {
        float w = ex[e];
        int vi = neigh[e];
        s += w;
        const float* row = u2e + (long)vi * 64 + cl * 8;
        float4 v0 = *(const float4*)row;
        float4 v1 = *(const float4*)(row + 4);
        a[0] = fmaf(w, v0.x, a[0]); a[1] = fmaf(w, v0.y, a[1]);
        a[2] = fmaf(w, v0.z, a[2]); a[3] = fmaf(w, v0.w, a[3]);
        a[4] = fmaf(w, v1.x, a[4]); a[5] = fmaf(w, v1.y, a[5]);
        a[6] = fmaf(w, v1.z, a[6]); a[7] = fmaf(w, v1.w, a[7]);
    }
#pragma unroll
    for (int msk = 8; msk <= 32; msk <<= 1) {
        s += __shfl_xor(s, msk);
#pragma unroll
        for (int j = 0; j < 8; ++j) a[j] += __shfl_xor(a[j], msk);
    }
    if (slot == 0) {
        float inv = 1.0f / fmaxf(s, 1e-9f);
        float4 o0 = {a[0] * inv, a[1] * inv, a[2] * inv, a[3] * inv};
        float4 o1 = {a[4] * inv, a[5] * inv, a[6] * inv, a[7] * inv};
        float* op = out + (long)n * 64 + cl * 8;
        *(float4*)op = o0;
        *(float4*)(op + 4) = o1;
    }
}

// ---------------- tier-3 fallback (tiny ws) -------------------------------------
__global__ void prep_bounds_k(const float* __restrict__ w1,
                              const float* __restrict__ w2,
                              const int* __restrict__ segs,
                              unsigned short* __restrict__ w1t,
                              unsigned short* __restrict__ w2t,
                              int* __restrict__ seg_off, int N, int E) {
    int t = threadIdx.x;
    if (blockIdx.x == 0) {
        for (int i = t; i < 128 * 64; i += 256) {
            int k = i >> 6, n = i & 63;
            w1t[n * 128 + k] = f2bf(w1[i]);
        }
        for (int i = t; i < 64 * 64; i += 256) {
            int k = i >> 6, n = i & 63;
            w2t[n * 64 + k] = f2bf(w2[i]);
        }
    } else {
        int idx = (blockIdx.x - 1) * 256 + t;
        if (idx > N) return;
        int l = 0, r = E;
        while (l < r) { int mid = (l + r) >> 1; if (segs[mid] < idx) l = mid + 1; else r = mid; }
        seg_off[idx] = l;
    }
}

__launch_bounds__(256)
__global__ void logits_fb_k(const int* __restrict__ nodes,
                            const int* __restrict__ neigh,
                            const int* __restrict__ segs,
                            const float* __restrict__ u2e,
                            const unsigned short* __restrict__ w1t,
                            const unsigned short* __restrict__ w2t,
                            const float* __restrict__ b1f, const float* __restrict__ b2f,
                            const float* __restrict__ w3f, const float* __restrict__ b3f,
                            float* __restrict__ ex, int E) {
    __shared__ __align__(16) unsigned short h1buf[4][16 * 72];
    const int wid = threadIdx.x >> 6;
    const int lane = threadIdx.x & 63;
    const int q = lane >> 4;
    const int m15 = lane & 15;
    const long base = ((long)blockIdx.x * 4 + wid) * 16;
    long ee0 = base + m15;
    int e = (int)(ee0 < E ? ee0 : (long)E - 1);
    int ni = neigh[e];
    int ctr = nodes[segs[e]];
    const float* eu = u2e + (long)ni * 64;
    const float* ur = u2e + (long)ctr * 64;
    bf16x8 a0 = cvt8(eu + q * 8), a1 = cvt8(eu + 32 + q * 8);
    bf16x8 a2 = cvt8(ur + q * 8), a3 = cvt8(ur + 32 + q * 8);
    f32x4 acc[4];
#pragma unroll
    for (int b = 0; b < 4; ++b) {
        float bvv = b1f[b * 16 + m15];
        acc[b] = (f32x4){bvv, bvv, bvv, bvv};
        const bf16x8* wrow = (const bf16x8*)(w1t + (b * 16 + m15) * 128);
        acc[b] = __builtin_amdgcn_mfma_f32_16x16x32_bf16(a0, wrow[0 + q], acc[b], 0, 0, 0);
        acc[b] = __builtin_amdgcn_mfma_f32_16x16x32_bf16(a1, wrow[4 + q], acc[b], 0, 0, 0);
        acc[b] = __builtin_amdgcn_mfma_f32_16x16x32_bf16(a2, wrow[8 + q], acc[b], 0, 0, 0);
        acc[b] = __builtin_amdgcn_mfma_f32_16x16x32_bf16(a3, wrow[12 + q], acc[b], 0, 0, 0);
    }
#pragma unroll
    for (int b = 0; b < 4; ++b)
#pragma unroll
        for (int r = 0; r < 4; ++r)
            h1buf[wid][(q * 4 + r) * 72 + b * 16 + m15] = f2bf(fmaxf(acc[b][r], 0.0f));
    const unsigned short* hrow = &h1buf[wid][m15 * 72];
    bf16x8 h0 = *(const bf16x8*)(hrow + q * 8);
    bf16x8 h1 = *(const bf16x8*)(hrow + 32 + q * 8);
    f32x4 acc2[4];
#pragma unroll
    for (int b = 0; b < 4; ++b) {
        float bvv = b2f[b * 16 + m15];
        acc2[b] = (f32x4){bvv, bvv, bvv, bvv};
        const bf16x8* wrow = (const bf16x8*)(w2t + (b * 16 + m15) * 64);
        acc2[b] = __builtin_amdgcn_mfma_f32_16x16x32_bf16(h0, wrow[0 + q], acc2[b], 0, 0, 0);
        acc2[b] = __builtin_amdgcn_mfma_f32_16x16x32_bf16(h1, wrow[4 + q], acc2[b], 0, 0, 0);
    }
    float b3v = b3f[0];
#pragma unroll
    for (int r = 0; r < 4; ++r) {
        float v = 0.0f;
#pragma unroll
        for (int b = 0; b < 4; ++b) v += fmaxf(acc2[b][r], 0.0f) * w3f[b * 16 + m15];
        v += __shfl_xor(v, 1);
        v += __shfl_xor(v, 2);
        v += __shfl_xor(v, 4);
        v += __shfl_xor(v, 8);
        long ee = base + q * 4 + r;
        if (m15 == r && ee < E) ex[ee] = __expf(v + b3v);
    }
}

extern "C" void kernel_launch(void* const* d_in, const int* in_sizes, int n_in,
                              void* d_out, int out_size, void* d_ws, size_t ws_size,
                              hipStream_t stream) {
    const int* nodes = (const int*)d_in[0];
    const int* neigh = (const int*)d_in[1];
    const int* segs  = (const int*)d_in[2];
    const float* u2e = (const float*)d_in[3];
    const float* w1  = (const float*)d_in[4];
    const float* b1  = (const float*)d_in[5];
    const float* w2  = (const float*)d_in[6];
    const float* b2  = (const float*)d_in[7];
    const float* w3  = (const float*)d_in[8];
    const float* b3  = (const float*)d_in[9];
    const int N = in_sizes[0];
    const int E = in_sizes[1];
    const long VD = in_sizes[3];
    const int V = (int)(VD / 64);

    char* ws = (char*)d_ws;
    size_t off = 0;
    auto alloc = [&](size_t bytes) { char* p = ws + off; off = (off + bytes + 255) & ~(size_t)255; return p; };
    float* ex = (float*)alloc((size_t)E * 4);
    int* seg_off = (int*)alloc((size_t)(N + 1) * 4);
    unsigned short* w1t = (unsigned short*)alloc(128 * 64 * 2);   // tier-3 only
    unsigned short* w2t = (unsigned short*)alloc(64 * 64 * 2);
    size_t need_min = off;
    unsigned short* Y = (unsigned short*)alloc((size_t)VD * 2);
    unsigned short* zb = (unsigned short*)alloc((size_t)N * 64 * 2);
    size_t need_t2 = off;
    unsigned short* u2ebf = (unsigned short*)alloc((size_t)VD * 2);
    float* den = (float*)alloc((size_t)N * 4);
    size_t need_t1 = off;
    (void)need_min;

    float* out = (float*)d_out;

    const int ytiles = (V + 63) / 64;
    const int ztiles = (N + 63) / 64;
    const int yblk = ytiles < 640 ? ytiles : 640;
    const int zblk = ztiles < 160 ? ztiles : 160;
    const int bblocks = (N + 256) / 256;
    const int lblocks = ((E + 31) / 32 + 3) / 4;
    const int ablocks = (N + 3) / 4;
    const int ZBLK = 128;

    if (ws_size >= need_t1) {
        conv_all_k<true><<<yblk + zblk + 1 + ZBLK, 256, 0, stream>>>(
            u2e, nodes, segs, w1, w2, b1, Y, u2ebf, zb, w2t, nullptr, out, den,
            V, N, E, yblk, zblk, ytiles, ztiles);
        fused_ea_k<<<lblocks, 256, 0, stream>>>(
            neigh, segs, Y, zb, u2ebf, w2t, b2, w3, b3, out, den, E);
        div_k<<<(N * 16 + 255) / 256, 256, 0, stream>>>(out, den, N);
    } else if (ws_size >= need_t2) {
        conv_all_k<false><<<yblk + zblk + 1 + bblocks, 256, 0, stream>>>(
            u2e, nodes, segs, w1, w2, b1, Y, nullptr, zb, w2t, seg_off, nullptr, nullptr,
            V, N, E, yblk, zblk, ytiles, ztiles);
        logits2_k<<<lblocks, 256, 0, stream>>>(neigh, segs, Y, zb, w2t, b2, w3, b3, ex, E);
        aggw_f32_k<<<ablocks, 256, 0, stream>>>(seg_off, neigh, u2e, ex, out, N);
    } else {
        const int pbblocks = 1 + (N + 256) / 256;
        prep_bounds_k<<<pbblocks, 256, 0, stream>>>(w1, w2, segs, w1t, w2t, seg_off, N, E);
        const int blocks1 = ((E + 15) / 16 + 3) / 4;
        logits_fb_k<<<blocks1, 256, 0, stream>>>(nodes, neigh, segs, u2e, w1t, w2t,
                                                 b1, b2, w3, b3, ex, E);
        aggw_f32_k<<<ablocks, 256, 0, stream>>>(seg_off, neigh, u2e, ex, out, N);
    }
}